// Round 4
// baseline (286.072 us; speedup 1.0000x reference)
//
#include <hip/hip_runtime.h>
#include <hip/hip_cooperative_groups.h>

namespace cg = cooperative_groups;

#define DIM    1024
#define BATCH  8
#define SEQ    2048
#define NBLK   512
#define NTHR   256
#define CHUNKS 64
#define ROWS   (SEQ / CHUNKS)   // 32 rows per phase-1 chunk
#define LN_EPS 1e-5f

typedef float v4 __attribute__((ext_vector_type(4)));

// ---------------------------------------------------------------------------
// Fused cooperative kernel: 5 phases with grid.sync between them.
//  P1 : partial column sums of x over s        (reads all of x -> fills L3)
//  P2a: finish column sum -> xsum[b,e]
//  P2b: vsum = xsum @ Wv^T
//  P2c: z    = vsum @ Wfc^T + b_fc
//  P3 : out  = LN(x + z) * gamma + beta        (x re-read: L3; NT store out)
// 512 blocks (2 blocks/CU at launch_bounds(256,4) cap of 4 -> 2x headroom).
// ---------------------------------------------------------------------------
__global__ __launch_bounds__(NTHR, 4) void k_fused(
    const float* __restrict__ x, const float* __restrict__ w_v,
    const float* __restrict__ w_fc, const float* __restrict__ b_fc,
    const float* __restrict__ gamma, const float* __restrict__ beta,
    float* __restrict__ out, float* __restrict__ ws) {
  cg::grid_group grid = cg::this_grid();
  const int blk = blockIdx.x, t = threadIdx.x;
  const int wv = t >> 6, lane = t & 63;

  float* partial = ws;                                   // CHUNKS*B*D floats
  float* xsum = partial + (size_t)CHUNKS * BATCH * DIM;  // B*D
  float* vsum = xsum + (size_t)BATCH * DIM;              // B*D
  float* z    = vsum + (size_t)BATCH * DIM;              // B*D

  // ---------------- Phase 1: partial col-sums (512 blocks = 8b x 64c) ------
  {
    int b = blk >> 6;
    int c = blk & (CHUNKS - 1);
    const v4* base =
        (const v4*)(x + ((size_t)b * SEQ + (size_t)c * ROWS) * DIM) + t;
    v4 acc = {0.f, 0.f, 0.f, 0.f};
#pragma unroll 8
    for (int s = 0; s < ROWS; ++s) acc += base[(size_t)s * (DIM / 4)];
    ((v4*)partial)[((size_t)c * BATCH + b) * (DIM / 4) + t] = acc;
  }
  grid.sync();

  // ---------------- Phase 2a: finish col-sum (64 blocks) -------------------
  if (blk < 64) {
    int i4 = blk * 32 + (t >> 3);  // v4 index over B*D/4 = 2048
    int c0 = t & 7;                // 8 threads split the 64 chunks
    const v4* p = (const v4*)partial;
    v4 acc = {0.f, 0.f, 0.f, 0.f};
#pragma unroll
    for (int k = 0; k < CHUNKS / 8; ++k)
      acc += p[(size_t)(c0 + 8 * k) * (BATCH * DIM / 4) + i4];
#pragma unroll
    for (int m = 4; m; m >>= 1) {
      acc.x += __shfl_xor(acc.x, m, 64);
      acc.y += __shfl_xor(acc.y, m, 64);
      acc.z += __shfl_xor(acc.z, m, 64);
      acc.w += __shfl_xor(acc.w, m, 64);
    }
    if (c0 == 0) ((v4*)xsum)[i4] = acc;
  }
  grid.sync();

  // ---------------- Phase 2b: vsum = xsum @ Wv^T (2048 waves x 4 out) ------
  {
    int w = blk * 4 + wv;
#pragma unroll
    for (int r = 0; r < 4; ++r) {
      int o = w * 4 + r;  // 0..8191
      int b = o >> 10, d = o & (DIM - 1);
      const v4* in4 = (const v4*)(xsum + (size_t)b * DIM);
      const v4* w4  = (const v4*)(w_v + (size_t)d * DIM);
      float acc = 0.f;
#pragma unroll
      for (int j = 0; j < 4; ++j) {
        v4 a = w4[lane + 64 * j], i = in4[lane + 64 * j];
        acc += a.x * i.x + a.y * i.y + a.z * i.z + a.w * i.w;
      }
#pragma unroll
      for (int m = 32; m; m >>= 1) acc += __shfl_xor(acc, m, 64);
      if (lane == 0) vsum[o] = acc;
    }
  }
  grid.sync();

  // ---------------- Phase 2c: z = vsum @ Wfc^T + b_fc ----------------------
  {
    int w = blk * 4 + wv;
#pragma unroll
    for (int r = 0; r < 4; ++r) {
      int o = w * 4 + r;
      int b = o >> 10, d = o & (DIM - 1);
      const v4* in4 = (const v4*)(vsum + (size_t)b * DIM);
      const v4* w4  = (const v4*)(w_fc + (size_t)d * DIM);
      float acc = 0.f;
#pragma unroll
      for (int j = 0; j < 4; ++j) {
        v4 a = w4[lane + 64 * j], i = in4[lane + 64 * j];
        acc += a.x * i.x + a.y * i.y + a.z * i.z + a.w * i.w;
      }
#pragma unroll
      for (int m = 32; m; m >>= 1) acc += __shfl_xor(acc, m, 64);
      if (lane == 0) z[o] = acc + b_fc[d];
    }
  }
  grid.sync();

  // ---------------- Phase 3: out = LN(x+z)*gamma + beta (8 rows/wave) ------
  {
    int gw = blk * 4 + wv;  // 0..2047
#pragma unroll 1
    for (int r = 0; r < 8; ++r) {
      int row = gw + r * 2048;  // consecutive waves -> consecutive rows
      int b = row >> 11;        // SEQ = 2048
      const v4* xr = (const v4*)(x + (size_t)row * DIM);
      const v4* zr = (const v4*)(z + (size_t)b * DIM);
      v4 h[4];
      float sum = 0.f, ss = 0.f;
#pragma unroll
      for (int j = 0; j < 4; ++j) {
        v4 hv = xr[lane + 64 * j] + zr[lane + 64 * j];
        h[j] = hv;
        sum += hv.x + hv.y + hv.z + hv.w;
        ss  += hv.x * hv.x + hv.y * hv.y + hv.z * hv.z + hv.w * hv.w;
      }
#pragma unroll
      for (int m = 32; m; m >>= 1) {
        sum += __shfl_xor(sum, m, 64);
        ss  += __shfl_xor(ss,  m, 64);
      }
      const float inv = 1.0f / (float)DIM;
      float mu = sum * inv;
      float rs = rsqrtf(ss * inv - mu * mu + LN_EPS);

      v4* outr = (v4*)out + (size_t)row * (DIM / 4);
#pragma unroll
      for (int j = 0; j < 4; ++j) {
        v4 g  = ((const v4*)gamma)[lane + 64 * j];
        v4 be = ((const v4*)beta)[lane + 64 * j];
        v4 o = (h[j] - mu) * rs * g + be;
        __builtin_nontemporal_store(o, &outr[lane + 64 * j]);
      }
    }
  }
}

// ------------------------- fallback (multi-kernel) -------------------------
__global__ __launch_bounds__(256) void k_partial_colsum(
    const float* __restrict__ x, float* __restrict__ partial) {
  int c = blockIdx.x, b = blockIdx.y, t = threadIdx.x;
  const v4* base =
      (const v4*)(x + ((size_t)b * SEQ + (size_t)c * ROWS) * DIM) + t;
  v4 acc = {0.f, 0.f, 0.f, 0.f};
#pragma unroll 8
  for (int s = 0; s < ROWS; ++s) acc += base[(size_t)s * (DIM / 4)];
  ((v4*)partial)[((size_t)c * BATCH + b) * (DIM / 4) + t] = acc;
}

__global__ __launch_bounds__(256) void k_finish_colsum(
    const float* __restrict__ partial, float* __restrict__ xsum) {
  int i4 = blockIdx.x * 256 + threadIdx.x;
  const v4* p = (const v4*)partial;
  v4 acc = {0.f, 0.f, 0.f, 0.f};
#pragma unroll 8
  for (int c = 0; c < CHUNKS; ++c) acc += p[(size_t)c * BATCH * (DIM / 4) + i4];
  ((v4*)xsum)[i4] = acc;
}

__global__ __launch_bounds__(256) void k_gemv(
    const float* __restrict__ vin, const float* __restrict__ W,
    const float* __restrict__ bias, float* __restrict__ vout) {
  int wave = threadIdx.x >> 6, lane = threadIdx.x & 63;
  int o = blockIdx.x * 4 + wave;
  int b = o >> 10, d = o & (DIM - 1);
  const v4* in4 = (const v4*)(vin + (size_t)b * DIM);
  const v4* w4  = (const v4*)(W + (size_t)d * DIM);
  float acc = 0.f;
#pragma unroll
  for (int j = 0; j < 4; ++j) {
    v4 w = w4[lane + 64 * j], i = in4[lane + 64 * j];
    acc += w.x * i.x + w.y * i.y + w.z * i.z + w.w * i.w;
  }
#pragma unroll
  for (int off = 32; off; off >>= 1) acc += __shfl_xor(acc, off, 64);
  if (lane == 0) {
    float r = acc;
    if (bias) r += bias[d];
    vout[o] = r;
  }
}

__global__ __launch_bounds__(256) void k_residual_ln(
    const float* __restrict__ x, const float* __restrict__ z,
    const float* __restrict__ gamma, const float* __restrict__ beta,
    float* __restrict__ out) {
  int wave = threadIdx.x >> 6, lane = threadIdx.x & 63;
  int row = blockIdx.x * 4 + wave;
  int b   = row >> 11;
  const v4* xr = (const v4*)(x + (size_t)row * DIM);
  const v4* zr = (const v4*)(z + (size_t)b * DIM);
  v4 h[4];
  float sum = 0.f, ss = 0.f;
#pragma unroll
  for (int j = 0; j < 4; ++j) {
    v4 hv = xr[lane + 64 * j] + zr[lane + 64 * j];
    h[j] = hv;
    sum += hv.x + hv.y + hv.z + hv.w;
    ss  += hv.x * hv.x + hv.y * hv.y + hv.z * hv.z + hv.w * hv.w;
  }
#pragma unroll
  for (int m = 32; m; m >>= 1) {
    sum += __shfl_xor(sum, m, 64);
    ss  += __shfl_xor(ss,  m, 64);
  }
  const float inv = 1.0f / (float)DIM;
  float mu = sum * inv;
  float rs = rsqrtf(ss * inv - mu * mu + LN_EPS);
  v4* outr = (v4*)out + (size_t)row * (DIM / 4);
#pragma unroll
  for (int j = 0; j < 4; ++j) {
    v4 g  = ((const v4*)gamma)[lane + 64 * j];
    v4 be = ((const v4*)beta)[lane + 64 * j];
    v4 o = (h[j] - mu) * rs * g + be;
    __builtin_nontemporal_store(o, &outr[lane + 64 * j]);
  }
}

extern "C" void kernel_launch(void* const* d_in, const int* in_sizes, int n_in,
                              void* d_out, int out_size, void* d_ws, size_t ws_size,
                              hipStream_t stream) {
  const float* x     = (const float*)d_in[0];   // [B, S, D]
  const float* w_qkv = (const float*)d_in[1];   // [3D, D]
  const float* w_fc  = (const float*)d_in[2];   // [D, D]
  const float* b_fc  = (const float*)d_in[3];   // [D]
  const float* gamma = (const float*)d_in[4];   // [D]
  const float* beta  = (const float*)d_in[5];   // [D]
  float* out = (float*)d_out;
  float* ws  = (float*)d_ws;

  const float* w_v = w_qkv + (size_t)2 * DIM * DIM;  // rows [2D,3D) of w_qkv

  void* args[] = {(void*)&x,     (void*)&w_v,  (void*)&w_fc, (void*)&b_fc,
                  (void*)&gamma, (void*)&beta, (void*)&out,  (void*)&ws};
  hipError_t err = hipLaunchCooperativeKernel((void*)k_fused, dim3(NBLK),
                                              dim3(NTHR), args, 0, stream);
  if (err != hipSuccess) {
    // Fallback: proven multi-kernel path (R1, 46 us).
    float* partial = ws;
    float* xsum    = partial + (size_t)CHUNKS * BATCH * DIM;
    float* vsum    = xsum + (size_t)BATCH * DIM;
    float* z       = vsum + (size_t)BATCH * DIM;
    hipLaunchKernelGGL(k_partial_colsum, dim3(CHUNKS, BATCH), dim3(256), 0,
                       stream, x, partial);
    hipLaunchKernelGGL(k_finish_colsum, dim3(BATCH * DIM / 4 / 256), dim3(256),
                       0, stream, partial, xsum);
    hipLaunchKernelGGL(k_gemv, dim3(BATCH * DIM / 4), dim3(256), 0, stream,
                       xsum, w_v, (const float*)nullptr, vsum);
    hipLaunchKernelGGL(k_gemv, dim3(BATCH * DIM / 4), dim3(256), 0, stream,
                       vsum, w_fc, b_fc, z);
    hipLaunchKernelGGL(k_residual_ln, dim3(BATCH * SEQ / 4), dim3(256), 0,
                       stream, x, z, gamma, beta, out);
  }
}